// Round 10
// baseline (105.310 us; speedup 1.0000x reference)
//
#include <hip/hip_runtime.h>
#include <hip/hip_bf16.h>

// Problem constants: N=8192 S=4 Z=64 H=128 K=4 DEG=16. Float tensors are f32.
typedef unsigned short u16;
typedef unsigned int u32;
using ushort8 = __attribute__((ext_vector_type(8))) unsigned short;
using short8  = __attribute__((ext_vector_type(8))) short;
using f32x4   = __attribute__((ext_vector_type(4))) float;

__device__ __forceinline__ float bf2f(u16 v) {
  union { u32 u; float f; } x; x.u = ((u32)v) << 16; return x.f;
}
__device__ __forceinline__ float u2f(u32 u) {
  union { u32 u; float f; } x; x.u = u; return x.f;
}
__device__ __forceinline__ u16 f2bf(float f) {
  union { u32 u; float f; } x; x.f = f;
  u32 r = x.u + 0x7FFFu + ((x.u >> 16) & 1u);  // RNE
  return (u16)(r >> 16);
}
__device__ __forceinline__ u32 pack2bf(float lo, float hi) {
  return (u32)f2bf(lo) | ((u32)f2bf(hi) << 16);
}
__device__ __forceinline__ float dot4(float4 a, float4 b) {
  return a.x * b.x + a.y * b.y + a.z * b.z + a.w * b.w;
}
// Split 8 f32 into bf16 hi (truncated) + bf16 lo (rounded residual): ~16-bit mantissa total.
__device__ __forceinline__ void split8(const float* ap, short8& hi, short8& lo) {
  float4 a0 = *(const float4*)ap, a1 = *(const float4*)(ap + 4);
  float e[8] = {a0.x, a0.y, a0.z, a0.w, a1.x, a1.y, a1.z, a1.w};
  u16 h[8], l[8];
  #pragma unroll
  for (int j = 0; j < 8; ++j) {
    u32 b = __float_as_uint(e[j]);
    h[j] = (u16)(b >> 16);
    l[j] = f2bf(e[j] - u2f(b & 0xffff0000u));
  }
  hi = *(short8*)h; lo = *(short8*)l;
}
// Stage a 128x64 f32 chunk into LDS bf16 [128][72], 256-thread version.
__device__ __forceinline__ void stage_w(const float* g, int stride, int c, u16* Wl, int t) {
  int row = t >> 1, half = t & 1;
  const float4* gp = (const float4*)(g + (size_t)row * stride + c * 64 + half * 32);
  ushort8* d = (ushort8*)(Wl + row * 72 + half * 32);
  #pragma unroll
  for (int i = 0; i < 4; ++i) {
    float4 a = gp[2 * i], b = gp[2 * i + 1];
    ushort8 o;
    o[0] = f2bf(a.x); o[1] = f2bf(a.y); o[2] = f2bf(a.z); o[3] = f2bf(a.w);
    o[4] = f2bf(b.x); o[5] = f2bf(b.y); o[6] = f2bf(b.z); o[7] = f2bf(b.w);
    d[i] = o;
  }
}
// Same, 512-thread version (each thread 16 cols of one row).
__device__ __forceinline__ void stage_w512(const float* g, int stride, int c, u16* Wl, int t) {
  int row = t >> 2, q = t & 3;
  const float4* gp = (const float4*)(g + (size_t)row * stride + c * 64 + q * 16);
  ushort8* d = (ushort8*)(Wl + row * 72 + q * 16);
  #pragma unroll
  for (int i = 0; i < 2; ++i) {
    float4 a = gp[2 * i], b = gp[2 * i + 1];
    ushort8 o;
    o[0] = f2bf(a.x); o[1] = f2bf(a.y); o[2] = f2bf(a.z); o[3] = f2bf(a.w);
    o[4] = f2bf(b.x); o[5] = f2bf(b.y); o[6] = f2bf(b.z); o[7] = f2bf(b.w);
    d[i] = o;
  }
}

// K_prep: blocks 0..63: B for td-GEMM, pre-split bf16 (Bh/Bl[(k*64+z1)*64+z2]);
//         blocks 64..319: WW2[ho][kk*128+hi] = (1/16) sum_j F1w1[ho][kk*128+j]*F2w2[j][hi]
__global__ __launch_bounds__(256) void k_prep(const float* __restrict__ Ws,
                                              const float* __restrict__ Wd,
                                              const float* __restrict__ F1w1,
                                              const float* __restrict__ F2w2,
                                              u16* __restrict__ Bh, u16* __restrict__ Bl,
                                              float* __restrict__ WW2) {
  if (blockIdx.x < 64) {
    int t = blockIdx.x * 256 + threadIdx.x;     // 16384 = k(4) x z1(64) x z2(64)
    int k = t >> 12, z1 = (t >> 6) & 63, z2 = t & 63;
    const float* wsp = Ws + k * 8192 + z1;
    const float* wdp = Wd + k * 8192 + z2;
    float acc = 0.f;
    #pragma unroll 8
    for (int h = 0; h < 128; ++h) acc += wsp[h * 64] * wdp[h * 64];
    u32 b = __float_as_uint(acc);
    Bh[(k * 64 + z1) * 64 + z2] = (u16)(b >> 16);
    Bl[(k * 64 + z1) * 64 + z2] = f2bf(acc - u2f(b & 0xffff0000u));
  } else {
    int id = (blockIdx.x - 64) * 256 + threadIdx.x;  // 65536 = 128 ho x 4 kk x 128 hi
    int ho = id >> 9, kk = (id >> 7) & 3, hi = id & 127;
    const float* wa = F1w1 + ho * 512 + kk * 128;
    const float* wb = F2w2 + hi;
    float acc = 0.f;
    #pragma unroll 8
    for (int j = 0; j < 128; ++j) acc += wa[j] * wb[j * 128];
    WW2[ho * 512 + kk * 128 + hi] = acc * 0.0625f;
  }
}

// K_tduv: blocks 0..511: td GEMM (f32-accurate split-bf16); blocks 512..767: uv GEMM.
__global__ __launch_bounds__(256) void k_tduv(const float* __restrict__ zIG,
                                              const u16* __restrict__ Bh_g,
                                              const u16* __restrict__ Bl_g,
                                              const float* __restrict__ xt,
                                              const float* __restrict__ W1,
                                              float* __restrict__ td,
                                              u16* __restrict__ u, u16* __restrict__ v) {
  __shared__ __align__(16) u16 WlA[128 * 72];
  __shared__ __align__(16) u16 WlB[128 * 72];
  int t = threadIdx.x, lane = t & 63, w = t >> 6;
  int l15 = lane & 15, kc = lane >> 4;
  if (blockIdx.x < 512) {
    u16* Bh = WlA;
    u16* Bl = WlB;
    int chalf = blockIdx.x & 1;
    size_t rowbase = (size_t)(blockIdx.x >> 1) * 128 + w * 32;
    {  // stage B col-half: 128 cols x 64 z2, hi+lo
      int row = t >> 1, half = t & 1;
      const ushort8* gh = (const ushort8*)(Bh_g + (chalf * 128 + row) * 64 + half * 32);
      const ushort8* gl = (const ushort8*)(Bl_g + (chalf * 128 + row) * 64 + half * 32);
      ushort8* dh = (ushort8*)(Bh + row * 72 + half * 32);
      ushort8* dl = (ushort8*)(Bl + row * 72 + half * 32);
      #pragma unroll
      for (int i = 0; i < 4; ++i) { dh[i] = gh[i]; dl[i] = gl[i]; }
    }
    __syncthreads();
    f32x4 acc[2][8];
    #pragma unroll
    for (int mt = 0; mt < 2; ++mt)
      #pragma unroll
      for (int nt = 0; nt < 8; ++nt) acc[mt][nt] = (f32x4){0.f, 0.f, 0.f, 0.f};
    #pragma unroll
    for (int ks = 0; ks < 2; ++ks) {
      short8 ah[2], al[2];
      #pragma unroll
      for (int mt = 0; mt < 2; ++mt)
        split8(zIG + (rowbase + mt * 16 + l15) * 64 + ks * 32 + kc * 8, ah[mt], al[mt]);
      #pragma unroll
      for (int nt = 0; nt < 8; ++nt) {
        int bo = (nt * 16 + l15) * 72 + ks * 32 + kc * 8;
        short8 bh = *(const short8*)&Bh[bo];
        short8 bl = *(const short8*)&Bl[bo];
        #pragma unroll
        for (int mt = 0; mt < 2; ++mt) {
          acc[mt][nt] = __builtin_amdgcn_mfma_f32_16x16x32_bf16(ah[mt], bh, acc[mt][nt], 0, 0, 0);
          acc[mt][nt] = __builtin_amdgcn_mfma_f32_16x16x32_bf16(al[mt], bh, acc[mt][nt], 0, 0, 0);
          acc[mt][nt] = __builtin_amdgcn_mfma_f32_16x16x32_bf16(ah[mt], bl, acc[mt][nt], 0, 0, 0);
        }
      }
    }
    #pragma unroll
    for (int mt = 0; mt < 2; ++mt)
      #pragma unroll
      for (int nt = 0; nt < 8; ++nt)
        #pragma unroll
        for (int j = 0; j < 4; ++j)
          td[(rowbase + mt * 16 + kc * 4 + j) * 256 + chalf * 128 + nt * 16 + l15] =
              acc[mt][nt][j];
  } else {
    u16* Wlu = WlA;
    u16* Wlv = WlB;
    size_t rowbase = (size_t)(blockIdx.x - 512) * 128 + w * 32;
    f32x4 au[2][8], av[2][8];
    #pragma unroll
    for (int mt = 0; mt < 2; ++mt)
      #pragma unroll
      for (int nt = 0; nt < 8; ++nt) {
        au[mt][nt] = (f32x4){0.f, 0.f, 0.f, 0.f};
        av[mt][nt] = (f32x4){0.f, 0.f, 0.f, 0.f};
      }
    for (int c = 0; c < 2; ++c) {
      __syncthreads();
      stage_w(W1,       256, c, Wlu, t);
      stage_w(W1 + 128, 256, c, Wlv, t);
      __syncthreads();
      #pragma unroll
      for (int ks = 0; ks < 2; ++ks) {
        short8 af[2];
        #pragma unroll
        for (int mt = 0; mt < 2; ++mt) {
          const float* ap = xt + (rowbase + mt * 16 + l15) * 128 + c * 64 + ks * 32 + kc * 8;
          float4 a0 = *(const float4*)ap, a1 = *(const float4*)(ap + 4);
          u16 tmp[8] = {f2bf(a0.x), f2bf(a0.y), f2bf(a0.z), f2bf(a0.w),
                        f2bf(a1.x), f2bf(a1.y), f2bf(a1.z), f2bf(a1.w)};
          af[mt] = *(short8*)tmp;
        }
        #pragma unroll
        for (int nt = 0; nt < 8; ++nt) {
          short8 bu = *(const short8*)&Wlu[(nt * 16 + l15) * 72 + ks * 32 + kc * 8];
          short8 bv = *(const short8*)&Wlv[(nt * 16 + l15) * 72 + ks * 32 + kc * 8];
          #pragma unroll
          for (int mt = 0; mt < 2; ++mt) {
            au[mt][nt] = __builtin_amdgcn_mfma_f32_16x16x32_bf16(af[mt], bu, au[mt][nt], 0, 0, 0);
            av[mt][nt] = __builtin_amdgcn_mfma_f32_16x16x32_bf16(af[mt], bv, av[mt][nt], 0, 0, 0);
          }
        }
      }
    }
    #pragma unroll
    for (int mt = 0; mt < 2; ++mt)
      #pragma unroll
      for (int nt = 0; nt < 8; ++nt)
        #pragma unroll
        for (int j = 0; j < 4; ++j) {
          size_t idx = (rowbase + mt * 16 + kc * 4 + j) * 128 + nt * 16 + l15;
          u[idx] = f2bf(au[mt][nt][j]);
          v[idx] = f2bf(av[mt][nt][j]);
        }
  }
}

// K_edge: per dst-node scores + softmax -> alpha (f32 exact). 2 barriers, ~5.5 KB LDS.
__global__ __launch_bounds__(256) void k_edge(
    const float* __restrict__ zIG, const int* __restrict__ src,
    const float* __restrict__ td, float* __restrict__ out) {
  __shared__ int srcIdx[16];
  __shared__ float tds[16 * 68];   // [sk][z] pad 68
  __shared__ float s17[16 * 17];   // scores [d][sk]

  int t = threadIdx.x, n = blockIdx.x;
  if (t < 16) srcIdx[t] = src[n * 16 + t];
  {
    int r = t >> 4, cc = t & 15;
    *(float4*)&tds[r * 68 + cc * 4] = ((const float4*)(td + (size_t)n * 1024))[r * 16 + cc];
  }
  __syncthreads();
  {  // phase B: scores + leaky_relu; quad lane k loads interleaved quarter of the z row.
    int d = t >> 4, s = (t >> 2) & 3, k = t & 3;
    int sn = srcIdx[d];
    const float4* zp = (const float4*)(zIG + (size_t)sn * 256 + s * 64);
    int base = s * 4;
    float p0 = 0.f, p1 = 0.f, p2 = 0.f, p3 = 0.f;
    #pragma unroll
    for (int i = 0; i < 4; ++i) {
      float4 zv = zp[i * 4 + k];
      int o = i * 16 + k * 4;
      p0 += dot4(zv, *(const float4*)&tds[(base + 0) * 68 + o]);
      p1 += dot4(zv, *(const float4*)&tds[(base + 1) * 68 + o]);
      p2 += dot4(zv, *(const float4*)&tds[(base + 2) * 68 + o]);
      p3 += dot4(zv, *(const float4*)&tds[(base + 3) * 68 + o]);
    }
    p0 += __shfl_xor(p0, 1); p1 += __shfl_xor(p1, 1);
    p2 += __shfl_xor(p2, 1); p3 += __shfl_xor(p3, 1);
    p0 += __shfl_xor(p0, 2); p1 += __shfl_xor(p1, 2);
    p2 += __shfl_xor(p2, 2); p3 += __shfl_xor(p3, 2);
    float acc = (k == 0) ? p0 : (k == 1) ? p1 : (k == 2) ? p2 : p3;
    s17[d * 17 + base + k] = acc > 0.f ? acc : 0.01f * acc;
  }
  __syncthreads();
  {  // phase C: per-thread redundant softmax over d (16 LDS reads + 16 __expf), alpha out
    int d = t >> 4, sk = t & 15;
    float mx = -3.4e38f;
    #pragma unroll
    for (int dd = 0; dd < 16; ++dd) mx = fmaxf(mx, s17[dd * 17 + sk]);
    float sum = 0.f, eown = 0.f;
    #pragma unroll
    for (int dd = 0; dd < 16; ++dd) {
      float e = __expf(s17[dd * 17 + sk] - mx);
      sum += e;
      if (dd == d) eown = e;
    }
    out[4194304u + (unsigned)n * 256 + t] = eown / sum;  // alpha [N][16][4][4]
  }
}

// K_mail: per dst-node mailbox m[sk][h] = sum_d alpha*relu(u[src]+v[n]) -> bf16 ws.
// One barrier, 1.3 KB LDS -> max occupancy; alpha re-read from out (coalesced).
__global__ __launch_bounds__(256) void k_mail(
    const int* __restrict__ src, const float* __restrict__ alpha_g,
    const u16* __restrict__ uW, const u16* __restrict__ vW, u16* __restrict__ m_ws) {
  __shared__ int srcIdx[16];
  __shared__ float al[256];
  int t = threadIdx.x, n = blockIdx.x;
  if (t < 16) srcIdx[t] = src[n * 16 + t];
  al[t] = alpha_g[(size_t)n * 256 + t];   // [d][s*4+k]
  __syncthreads();
  int hp = t & 63, s = t >> 6;            // s wave-uniform -> LDS broadcasts
  u32 vbits = *(const u32*)(vW + (size_t)n * 512 + s * 128 + hp * 2);
  float v_lo = u2f(vbits << 16), v_hi = u2f(vbits & 0xffff0000u);
  const u32* up = (const u32*)uW;
  float m0l = 0.f, m0h = 0.f, m1l = 0.f, m1h = 0.f;
  float m2l = 0.f, m2h = 0.f, m3l = 0.f, m3h = 0.f;
  #pragma unroll
  for (int d = 0; d < 16; ++d) {
    u32 ub = up[(size_t)srcIdx[d] * 256 + s * 64 + hp];
    float r_lo = fmaxf(u2f(ub << 16) + v_lo, 0.f);
    float r_hi = fmaxf(u2f(ub & 0xffff0000u) + v_hi, 0.f);
    float4 a = *(const float4*)&al[d * 16 + s * 4];
    m0l += a.x * r_lo; m0h += a.x * r_hi;
    m1l += a.y * r_lo; m1h += a.y * r_hi;
    m2l += a.z * r_lo; m2h += a.z * r_hi;
    m3l += a.w * r_lo; m3h += a.w * r_hi;
  }
  u32* mp = (u32*)(m_ws + (size_t)n * 2048);
  mp[(s * 4 + 0) * 64 + hp] = pack2bf(m0l, m0h);
  mp[(s * 4 + 1) * 64 + hp] = pack2bf(m1l, m1h);
  mp[(s * 4 + 2) * 64 + hp] = pack2bf(m2l, m2h);
  mp[(s * 4 + 3) * 64 + hp] = pack2bf(m3l, m3h);
}

// K4: fused F+G, 512 threads / 8 waves (16 rows per wave).
//   hid = relu(m_flat[row][512] @ WW2[128][512]^T); out = hid @ F1w2[128][128]^T
__global__ __launch_bounds__(512) void k_fg(const u16* __restrict__ A,
                                            const float* __restrict__ WF,
                                            const float* __restrict__ WG,
                                            float* __restrict__ out) {
  __shared__ u16 Wl[128 * 72];
  __shared__ u16 hidl[128 * 136];
  int t = threadIdx.x, lane = t & 63, w = t >> 6;
  size_t rowbase = (size_t)blockIdx.x * 128 + w * 16;
  int l15 = lane & 15, kc = lane >> 4;
  f32x4 acc[8];
  #pragma unroll
  for (int nt = 0; nt < 8; ++nt) acc[nt] = (f32x4){0.f, 0.f, 0.f, 0.f};
  for (int c = 0; c < 8; ++c) {
    __syncthreads();
    stage_w512(WF, 512, c, Wl, t);
    __syncthreads();
    #pragma unroll
    for (int ks = 0; ks < 2; ++ks) {
      short8 af = *(const short8*)(A + (rowbase + l15) * 512 + c * 64 + ks * 32 + kc * 8);
      #pragma unroll
      for (int nt = 0; nt < 8; ++nt) {
        short8 bf = *(const short8*)&Wl[(nt * 16 + l15) * 72 + ks * 32 + kc * 8];
        acc[nt] = __builtin_amdgcn_mfma_f32_16x16x32_bf16(af, bf, acc[nt], 0, 0, 0);
      }
    }
  }
  #pragma unroll
  for (int nt = 0; nt < 8; ++nt)
    #pragma unroll
    for (int j = 0; j < 4; ++j)
      hidl[(w * 16 + kc * 4 + j) * 136 + nt * 16 + l15] = f2bf(fmaxf(acc[nt][j], 0.f));
  f32x4 acc2[8];
  #pragma unroll
  for (int nt = 0; nt < 8; ++nt) acc2[nt] = (f32x4){0.f, 0.f, 0.f, 0.f};
  for (int c = 0; c < 2; ++c) {
    __syncthreads();
    stage_w512(WG, 128, c, Wl, t);
    __syncthreads();
    #pragma unroll
    for (int ks = 0; ks < 2; ++ks) {
      short8 af = *(const short8*)&hidl[(w * 16 + l15) * 136 + c * 64 + ks * 32 + kc * 8];
      #pragma unroll
      for (int nt = 0; nt < 8; ++nt) {
        short8 bf = *(const short8*)&Wl[(nt * 16 + l15) * 72 + ks * 32 + kc * 8];
        acc2[nt] = __builtin_amdgcn_mfma_f32_16x16x32_bf16(af, bf, acc2[nt], 0, 0, 0);
      }
    }
  }
  #pragma unroll
  for (int nt = 0; nt < 8; ++nt)
    #pragma unroll
    for (int j = 0; j < 4; ++j)
      out[(rowbase + kc * 4 + j) * 128 + nt * 16 + l15] = acc2[nt][j];
}

extern "C" void kernel_launch(void* const* d_in, const int* in_sizes, int n_in,
                              void* d_out, int out_size, void* d_ws, size_t ws_size,
                              hipStream_t stream) {
  const float* zIG  = (const float*)d_in[0];
  const float* xt   = (const float*)d_in[1];
  const float* Ws   = (const float*)d_in[2];
  const float* Wd   = (const float*)d_in[3];
  const float* F2w1 = (const float*)d_in[4];
  const float* F2w2 = (const float*)d_in[5];
  const float* F1w1 = (const float*)d_in[6];
  const float* F1w2 = (const float*)d_in[7];
  const int* src    = (const int*)d_in[8];
  float* out = (float*)d_out;

  char* ws = (char*)d_ws;
  u16* Bh    = (u16*)ws;                             // 32 KiB (td-GEMM B hi)
  u16* Bl    = Bh + 16384;                           // 32 KiB (td-GEMM B lo)
  float* td  = (float*)(ws + 65536);                 // 32 MiB
  u16* u     = (u16*)(ws + 65536 + 33554432);        // 8 MiB
  u16* v     = u + 4194304;                          // 8 MiB
  float* WW2 = (float*)(ws + 50397184);              // 256 KiB (composite F1w1@F2w2/16)
  u16* m     = (u16*)(ws + 50659328);                // 32 MiB

  k_prep <<<320,  256, 0, stream>>>(Ws, Wd, F1w1, F2w2, Bh, Bl, WW2);
  k_tduv <<<768,  256, 0, stream>>>(zIG, Bh, Bl, xt, F2w1, td, u, v);
  k_edge <<<8192, 256, 0, stream>>>(zIG, src, td, out);
  k_mail <<<8192, 256, 0, stream>>>(src, out + 4194304, u, v, m);
  k_fg   <<<256,  512, 0, stream>>>(m, WW2, F1w2, out);
}

// Round 11
// 104.087 us; speedup vs baseline: 1.0117x; 1.0117x over previous
//
#include <hip/hip_runtime.h>
#include <hip/hip_bf16.h>

// Problem constants: N=8192 S=4 Z=64 H=128 K=4 DEG=16. Float tensors are f32.
typedef unsigned short u16;
typedef unsigned int u32;
using ushort8 = __attribute__((ext_vector_type(8))) unsigned short;
using short8  = __attribute__((ext_vector_type(8))) short;
using f32x4   = __attribute__((ext_vector_type(4))) float;

__device__ __forceinline__ float bf2f(u16 v) {
  union { u32 u; float f; } x; x.u = ((u32)v) << 16; return x.f;
}
__device__ __forceinline__ float u2f(u32 u) {
  union { u32 u; float f; } x; x.u = u; return x.f;
}
__device__ __forceinline__ u16 f2bf(float f) {
  union { u32 u; float f; } x; x.f = f;
  u32 r = x.u + 0x7FFFu + ((x.u >> 16) & 1u);  // RNE
  return (u16)(r >> 16);
}
__device__ __forceinline__ u32 pack2bf(float lo, float hi) {
  return (u32)f2bf(lo) | ((u32)f2bf(hi) << 16);
}
__device__ __forceinline__ float dot4(float4 a, float4 b) {
  return a.x * b.x + a.y * b.y + a.z * b.z + a.w * b.w;
}
// Split 8 f32 into bf16 hi (truncated) + bf16 lo (rounded residual): ~16-bit mantissa total.
__device__ __forceinline__ void split8(const float* ap, short8& hi, short8& lo) {
  float4 a0 = *(const float4*)ap, a1 = *(const float4*)(ap + 4);
  float e[8] = {a0.x, a0.y, a0.z, a0.w, a1.x, a1.y, a1.z, a1.w};
  u16 h[8], l[8];
  #pragma unroll
  for (int j = 0; j < 8; ++j) {
    u32 b = __float_as_uint(e[j]);
    h[j] = (u16)(b >> 16);
    l[j] = f2bf(e[j] - u2f(b & 0xffff0000u));
  }
  hi = *(short8*)h; lo = *(short8*)l;
}
// Stage a 128x64 f32 chunk into LDS bf16 [128][72], 256-thread version.
__device__ __forceinline__ void stage_w(const float* g, int stride, int c, u16* Wl, int t) {
  int row = t >> 1, half = t & 1;
  const float4* gp = (const float4*)(g + (size_t)row * stride + c * 64 + half * 32);
  ushort8* d = (ushort8*)(Wl + row * 72 + half * 32);
  #pragma unroll
  for (int i = 0; i < 4; ++i) {
    float4 a = gp[2 * i], b = gp[2 * i + 1];
    ushort8 o;
    o[0] = f2bf(a.x); o[1] = f2bf(a.y); o[2] = f2bf(a.z); o[3] = f2bf(a.w);
    o[4] = f2bf(b.x); o[5] = f2bf(b.y); o[6] = f2bf(b.z); o[7] = f2bf(b.w);
    d[i] = o;
  }
}
// Same, 512-thread version (each thread 16 cols of one row).
__device__ __forceinline__ void stage_w512(const float* g, int stride, int c, u16* Wl, int t) {
  int row = t >> 2, q = t & 3;
  const float4* gp = (const float4*)(g + (size_t)row * stride + c * 64 + q * 16);
  ushort8* d = (ushort8*)(Wl + row * 72 + q * 16);
  #pragma unroll
  for (int i = 0; i < 2; ++i) {
    float4 a = gp[2 * i], b = gp[2 * i + 1];
    ushort8 o;
    o[0] = f2bf(a.x); o[1] = f2bf(a.y); o[2] = f2bf(a.z); o[3] = f2bf(a.w);
    o[4] = f2bf(b.x); o[5] = f2bf(b.y); o[6] = f2bf(b.z); o[7] = f2bf(b.w);
    d[i] = o;
  }
}

// K_prep: blocks 0..63: B for td-GEMM, pre-split bf16 (Bh/Bl[(k*64+z1)*64+z2]);
//         blocks 64..319: WW2[ho][kk*128+hi] = (1/16) sum_j F1w1[ho][kk*128+j]*F2w2[j][hi]
__global__ __launch_bounds__(256) void k_prep(const float* __restrict__ Ws,
                                              const float* __restrict__ Wd,
                                              const float* __restrict__ F1w1,
                                              const float* __restrict__ F2w2,
                                              u16* __restrict__ Bh, u16* __restrict__ Bl,
                                              float* __restrict__ WW2) {
  if (blockIdx.x < 64) {
    int t = blockIdx.x * 256 + threadIdx.x;     // 16384 = k(4) x z1(64) x z2(64)
    int k = t >> 12, z1 = (t >> 6) & 63, z2 = t & 63;
    const float* wsp = Ws + k * 8192 + z1;
    const float* wdp = Wd + k * 8192 + z2;
    float acc = 0.f;
    #pragma unroll 8
    for (int h = 0; h < 128; ++h) acc += wsp[h * 64] * wdp[h * 64];
    u32 b = __float_as_uint(acc);
    Bh[(k * 64 + z1) * 64 + z2] = (u16)(b >> 16);
    Bl[(k * 64 + z1) * 64 + z2] = f2bf(acc - u2f(b & 0xffff0000u));
  } else {
    int id = (blockIdx.x - 64) * 256 + threadIdx.x;  // 65536 = 128 ho x 4 kk x 128 hi
    int ho = id >> 9, kk = (id >> 7) & 3, hi = id & 127;
    const float* wa = F1w1 + ho * 512 + kk * 128;
    const float* wb = F2w2 + hi;
    float acc = 0.f;
    #pragma unroll 8
    for (int j = 0; j < 128; ++j) acc += wa[j] * wb[j * 128];
    WW2[ho * 512 + kk * 128 + hi] = acc * 0.0625f;
  }
}

// K_tduv, small-tile version for occupancy (18.4 KB LDS, modest VGPR, grid 1536):
//  blocks 0..1023:  td tile = 128 rows x 64 cols. rowtile=bid>>2, colquarter=bid&3.
//  blocks 1024..1535: u or v tile = 128 rows x 128 cols. sel=(bid-1024)>>8.
__global__ __launch_bounds__(256) void k_tduv(const float* __restrict__ zIG,
                                              const u16* __restrict__ Bh_g,
                                              const u16* __restrict__ Bl_g,
                                              const float* __restrict__ xt,
                                              const float* __restrict__ W1,
                                              float* __restrict__ td,
                                              u16* __restrict__ u, u16* __restrict__ v) {
  __shared__ __align__(16) u16 SM[128 * 72];   // td: Bh=SM[0:64*72), Bl=SM[64*72:); uv: full Wl
  int t = threadIdx.x, lane = t & 63, w = t >> 6;
  int l15 = lane & 15, kc = lane >> 4;
  if (blockIdx.x < 1024) {
    u16* Bh = SM;
    u16* Bl = SM + 64 * 72;
    int cq = blockIdx.x & 3;
    size_t rowbase = (size_t)(blockIdx.x >> 2) * 128 + w * 32;
    {  // stage B quarter: 64 cols x 64 z2, hi+lo
      int row = t >> 2, q = t & 3;
      const ushort8* gh = (const ushort8*)(Bh_g + (cq * 64 + row) * 64 + q * 16);
      const ushort8* gl = (const ushort8*)(Bl_g + (cq * 64 + row) * 64 + q * 16);
      ushort8* dh = (ushort8*)(Bh + row * 72 + q * 16);
      ushort8* dl = (ushort8*)(Bl + row * 72 + q * 16);
      dh[0] = gh[0]; dh[1] = gh[1];
      dl[0] = gl[0]; dl[1] = gl[1];
    }
    __syncthreads();
    f32x4 acc[2][4];
    #pragma unroll
    for (int mt = 0; mt < 2; ++mt)
      #pragma unroll
      for (int nt = 0; nt < 4; ++nt) acc[mt][nt] = (f32x4){0.f, 0.f, 0.f, 0.f};
    #pragma unroll
    for (int ks = 0; ks < 2; ++ks) {
      short8 ah[2], al[2];
      #pragma unroll
      for (int mt = 0; mt < 2; ++mt)
        split8(zIG + (rowbase + mt * 16 + l15) * 64 + ks * 32 + kc * 8, ah[mt], al[mt]);
      #pragma unroll
      for (int nt = 0; nt < 4; ++nt) {
        int bo = (nt * 16 + l15) * 72 + ks * 32 + kc * 8;
        short8 bh = *(const short8*)&Bh[bo];
        short8 bl = *(const short8*)&Bl[bo];
        #pragma unroll
        for (int mt = 0; mt < 2; ++mt) {
          acc[mt][nt] = __builtin_amdgcn_mfma_f32_16x16x32_bf16(ah[mt], bh, acc[mt][nt], 0, 0, 0);
          acc[mt][nt] = __builtin_amdgcn_mfma_f32_16x16x32_bf16(al[mt], bh, acc[mt][nt], 0, 0, 0);
          acc[mt][nt] = __builtin_amdgcn_mfma_f32_16x16x32_bf16(ah[mt], bl, acc[mt][nt], 0, 0, 0);
        }
      }
    }
    #pragma unroll
    for (int mt = 0; mt < 2; ++mt)
      #pragma unroll
      for (int nt = 0; nt < 4; ++nt)
        #pragma unroll
        for (int j = 0; j < 4; ++j)
          td[(rowbase + mt * 16 + kc * 4 + j) * 256 + cq * 64 + nt * 16 + l15] =
              acc[mt][nt][j];
  } else {
    u16* Wl = SM;
    int bid2 = blockIdx.x - 1024;
    int sel = bid2 >> 8;                       // 0 = u, 1 = v
    size_t rowbase = (size_t)(bid2 & 255) * 128 + w * 32;
    const float* Wbase = W1 + sel * 128;
    f32x4 acc[2][8];
    #pragma unroll
    for (int mt = 0; mt < 2; ++mt)
      #pragma unroll
      for (int nt = 0; nt < 8; ++nt) acc[mt][nt] = (f32x4){0.f, 0.f, 0.f, 0.f};
    for (int c = 0; c < 2; ++c) {
      __syncthreads();
      stage_w(Wbase, 256, c, Wl, t);
      __syncthreads();
      #pragma unroll
      for (int ks = 0; ks < 2; ++ks) {
        short8 af[2];
        #pragma unroll
        for (int mt = 0; mt < 2; ++mt) {
          const float* ap = xt + (rowbase + mt * 16 + l15) * 128 + c * 64 + ks * 32 + kc * 8;
          float4 a0 = *(const float4*)ap, a1 = *(const float4*)(ap + 4);
          u16 tmp[8] = {f2bf(a0.x), f2bf(a0.y), f2bf(a0.z), f2bf(a0.w),
                        f2bf(a1.x), f2bf(a1.y), f2bf(a1.z), f2bf(a1.w)};
          af[mt] = *(short8*)tmp;
        }
        #pragma unroll
        for (int nt = 0; nt < 8; ++nt) {
          short8 bw = *(const short8*)&Wl[(nt * 16 + l15) * 72 + ks * 32 + kc * 8];
          #pragma unroll
          for (int mt = 0; mt < 2; ++mt)
            acc[mt][nt] = __builtin_amdgcn_mfma_f32_16x16x32_bf16(af[mt], bw, acc[mt][nt], 0, 0, 0);
        }
      }
    }
    u16* dstp = sel ? v : u;
    #pragma unroll
    for (int mt = 0; mt < 2; ++mt)
      #pragma unroll
      for (int nt = 0; nt < 8; ++nt)
        #pragma unroll
        for (int j = 0; j < 4; ++j)
          dstp[(rowbase + mt * 16 + kc * 4 + j) * 128 + nt * 16 + l15] =
              f2bf(acc[mt][nt][j]);
  }
}

// K_edge: per dst-node scores + softmax -> alpha (f32 exact). 2 barriers, ~5.5 KB LDS.
__global__ __launch_bounds__(256) void k_edge(
    const float* __restrict__ zIG, const int* __restrict__ src,
    const float* __restrict__ td, float* __restrict__ out) {
  __shared__ int srcIdx[16];
  __shared__ float tds[16 * 68];   // [sk][z] pad 68
  __shared__ float s17[16 * 17];   // scores [d][sk]

  int t = threadIdx.x, n = blockIdx.x;
  if (t < 16) srcIdx[t] = src[n * 16 + t];
  {
    int r = t >> 4, cc = t & 15;
    *(float4*)&tds[r * 68 + cc * 4] = ((const float4*)(td + (size_t)n * 1024))[r * 16 + cc];
  }
  __syncthreads();
  {  // phase B: scores + leaky_relu; quad lane k loads interleaved quarter of the z row.
    int d = t >> 4, s = (t >> 2) & 3, k = t & 3;
    int sn = srcIdx[d];
    const float4* zp = (const float4*)(zIG + (size_t)sn * 256 + s * 64);
    int base = s * 4;
    float p0 = 0.f, p1 = 0.f, p2 = 0.f, p3 = 0.f;
    #pragma unroll
    for (int i = 0; i < 4; ++i) {
      float4 zv = zp[i * 4 + k];
      int o = i * 16 + k * 4;
      p0 += dot4(zv, *(const float4*)&tds[(base + 0) * 68 + o]);
      p1 += dot4(zv, *(const float4*)&tds[(base + 1) * 68 + o]);
      p2 += dot4(zv, *(const float4*)&tds[(base + 2) * 68 + o]);
      p3 += dot4(zv, *(const float4*)&tds[(base + 3) * 68 + o]);
    }
    p0 += __shfl_xor(p0, 1); p1 += __shfl_xor(p1, 1);
    p2 += __shfl_xor(p2, 1); p3 += __shfl_xor(p3, 1);
    p0 += __shfl_xor(p0, 2); p1 += __shfl_xor(p1, 2);
    p2 += __shfl_xor(p2, 2); p3 += __shfl_xor(p3, 2);
    float acc = (k == 0) ? p0 : (k == 1) ? p1 : (k == 2) ? p2 : p3;
    s17[d * 17 + base + k] = acc > 0.f ? acc : 0.01f * acc;
  }
  __syncthreads();
  {  // phase C: per-thread redundant softmax over d (16 LDS reads + 16 __expf), alpha out
    int d = t >> 4, sk = t & 15;
    float mx = -3.4e38f;
    #pragma unroll
    for (int dd = 0; dd < 16; ++dd) mx = fmaxf(mx, s17[dd * 17 + sk]);
    float sum = 0.f, eown = 0.f;
    #pragma unroll
    for (int dd = 0; dd < 16; ++dd) {
      float e = __expf(s17[dd * 17 + sk] - mx);
      sum += e;
      if (dd == d) eown = e;
    }
    out[4194304u + (unsigned)n * 256 + t] = eown / sum;  // alpha [N][16][4][4]
  }
}

// K_mail: per dst-node mailbox m[sk][h] = sum_d alpha*relu(u[src]+v[n]) -> bf16 ws.
// One barrier, 1.3 KB LDS -> max occupancy; alpha re-read from out (coalesced).
__global__ __launch_bounds__(256) void k_mail(
    const int* __restrict__ src, const float* __restrict__ alpha_g,
    const u16* __restrict__ uW, const u16* __restrict__ vW, u16* __restrict__ m_ws) {
  __shared__ int srcIdx[16];
  __shared__ float al[256];
  int t = threadIdx.x, n = blockIdx.x;
  if (t < 16) srcIdx[t] = src[n * 16 + t];
  al[t] = alpha_g[(size_t)n * 256 + t];   // [d][s*4+k]
  __syncthreads();
  int hp = t & 63, s = t >> 6;            // s wave-uniform -> LDS broadcasts
  u32 vbits = *(const u32*)(vW + (size_t)n * 512 + s * 128 + hp * 2);
  float v_lo = u2f(vbits << 16), v_hi = u2f(vbits & 0xffff0000u);
  const u32* up = (const u32*)uW;
  float m0l = 0.f, m0h = 0.f, m1l = 0.f, m1h = 0.f;
  float m2l = 0.f, m2h = 0.f, m3l = 0.f, m3h = 0.f;
  #pragma unroll
  for (int d = 0; d < 16; ++d) {
    u32 ub = up[(size_t)srcIdx[d] * 256 + s * 64 + hp];
    float r_lo = fmaxf(u2f(ub << 16) + v_lo, 0.f);
    float r_hi = fmaxf(u2f(ub & 0xffff0000u) + v_hi, 0.f);
    float4 a = *(const float4*)&al[d * 16 + s * 4];
    m0l += a.x * r_lo; m0h += a.x * r_hi;
    m1l += a.y * r_lo; m1h += a.y * r_hi;
    m2l += a.z * r_lo; m2h += a.z * r_hi;
    m3l += a.w * r_lo; m3h += a.w * r_hi;
  }
  u32* mp = (u32*)(m_ws + (size_t)n * 2048);
  mp[(s * 4 + 0) * 64 + hp] = pack2bf(m0l, m0h);
  mp[(s * 4 + 1) * 64 + hp] = pack2bf(m1l, m1h);
  mp[(s * 4 + 2) * 64 + hp] = pack2bf(m2l, m2h);
  mp[(s * 4 + 3) * 64 + hp] = pack2bf(m3l, m3h);
}

// K4: fused F+G, 512 threads / 8 waves (16 rows per wave).
//   hid = relu(m_flat[row][512] @ WW2[128][512]^T); out = hid @ F1w2[128][128]^T
__global__ __launch_bounds__(512) void k_fg(const u16* __restrict__ A,
                                            const float* __restrict__ WF,
                                            const float* __restrict__ WG,
                                            float* __restrict__ out) {
  __shared__ u16 Wl[128 * 72];
  __shared__ u16 hidl[128 * 136];
  int t = threadIdx.x, lane = t & 63, w = t >> 6;
  size_t rowbase = (size_t)blockIdx.x * 128 + w * 16;
  int l15 = lane & 15, kc = lane >> 4;
  f32x4 acc[8];
  #pragma unroll
  for (int nt = 0; nt < 8; ++nt) acc[nt] = (f32x4){0.f, 0.f, 0.f, 0.f};
  for (int c = 0; c < 8; ++c) {
    __syncthreads();
    stage_w512(WF, 512, c, Wl, t);
    __syncthreads();
    #pragma unroll
    for (int ks = 0; ks < 2; ++ks) {
      short8 af = *(const short8*)(A + (rowbase + l15) * 512 + c * 64 + ks * 32 + kc * 8);
      #pragma unroll
      for (int nt = 0; nt < 8; ++nt) {
        short8 bf = *(const short8*)&Wl[(nt * 16 + l15) * 72 + ks * 32 + kc * 8];
        acc[nt] = __builtin_amdgcn_mfma_f32_16x16x32_bf16(af, bf, acc[nt], 0, 0, 0);
      }
    }
  }
  #pragma unroll
  for (int nt = 0; nt < 8; ++nt)
    #pragma unroll
    for (int j = 0; j < 4; ++j)
      hidl[(w * 16 + kc * 4 + j) * 136 + nt * 16 + l15] = f2bf(fmaxf(acc[nt][j], 0.f));
  f32x4 acc2[8];
  #pragma unroll
  for (int nt = 0; nt < 8; ++nt) acc2[nt] = (f32x4){0.f, 0.f, 0.f, 0.f};
  for (int c = 0; c < 2; ++c) {
    __syncthreads();
    stage_w512(WG, 128, c, Wl, t);
    __syncthreads();
    #pragma unroll
    for (int ks = 0; ks < 2; ++ks) {
      short8 af = *(const short8*)&hidl[(w * 16 + l15) * 136 + c * 64 + ks * 32 + kc * 8];
      #pragma unroll
      for (int nt = 0; nt < 8; ++nt) {
        short8 bf = *(const short8*)&Wl[(nt * 16 + l15) * 72 + ks * 32 + kc * 8];
        acc2[nt] = __builtin_amdgcn_mfma_f32_16x16x32_bf16(af, bf, acc2[nt], 0, 0, 0);
      }
    }
  }
  #pragma unroll
  for (int nt = 0; nt < 8; ++nt)
    #pragma unroll
    for (int j = 0; j < 4; ++j)
      out[(rowbase + kc * 4 + j) * 128 + nt * 16 + l15] = acc2[nt][j];
}

extern "C" void kernel_launch(void* const* d_in, const int* in_sizes, int n_in,
                              void* d_out, int out_size, void* d_ws, size_t ws_size,
                              hipStream_t stream) {
  const float* zIG  = (const float*)d_in[0];
  const float* xt   = (const float*)d_in[1];
  const float* Ws   = (const float*)d_in[2];
  const float* Wd   = (const float*)d_in[3];
  const float* F2w1 = (const float*)d_in[4];
  const float* F2w2 = (const float*)d_in[5];
  const float* F1w1 = (const float*)d_in[6];
  const float* F1w2 = (const float*)d_in[7];
  const int* src    = (const int*)d_in[8];
  float* out = (float*)d_out;

  char* ws = (char*)d_ws;
  u16* Bh    = (u16*)ws;                             // 32 KiB (td-GEMM B hi)
  u16* Bl    = Bh + 16384;                           // 32 KiB (td-GEMM B lo)
  float* td  = (float*)(ws + 65536);                 // 32 MiB
  u16* u     = (u16*)(ws + 65536 + 33554432);        // 8 MiB
  u16* v     = u + 4194304;                          // 8 MiB
  float* WW2 = (float*)(ws + 50397184);              // 256 KiB (composite F1w1@F2w2/16)
  u16* m     = (u16*)(ws + 50659328);                // 32 MiB

  k_prep <<<320,  256, 0, stream>>>(Ws, Wd, F1w1, F2w2, Bh, Bl, WW2);
  k_tduv <<<1536, 256, 0, stream>>>(zIG, Bh, Bl, xt, F2w1, td, u, v);
  k_edge <<<8192, 256, 0, stream>>>(zIG, src, td, out);
  k_mail <<<8192, 256, 0, stream>>>(src, out + 4194304, u, v, m);
  k_fg   <<<256,  512, 0, stream>>>(m, WW2, F1w2, out);
}

// Round 12
// 100.470 us; speedup vs baseline: 1.0482x; 1.0360x over previous
//
#include <hip/hip_runtime.h>
#include <hip/hip_bf16.h>

// Problem constants: N=8192 S=4 Z=64 H=128 K=4 DEG=16. Float tensors are f32.
typedef unsigned short u16;
typedef unsigned int u32;
using ushort8 = __attribute__((ext_vector_type(8))) unsigned short;
using short8  = __attribute__((ext_vector_type(8))) short;
using f32x4   = __attribute__((ext_vector_type(4))) float;

__device__ __forceinline__ float bf2f(u16 v) {
  union { u32 u; float f; } x; x.u = ((u32)v) << 16; return x.f;
}
__device__ __forceinline__ float u2f(u32 u) {
  union { u32 u; float f; } x; x.u = u; return x.f;
}
__device__ __forceinline__ u16 f2bf(float f) {
  union { u32 u; float f; } x; x.f = f;
  u32 r = x.u + 0x7FFFu + ((x.u >> 16) & 1u);  // RNE
  return (u16)(r >> 16);
}
__device__ __forceinline__ u32 pack2bf(float lo, float hi) {
  return (u32)f2bf(lo) | ((u32)f2bf(hi) << 16);
}
__device__ __forceinline__ float dot4(float4 a, float4 b) {
  return a.x * b.x + a.y * b.y + a.z * b.z + a.w * b.w;
}
// Split 8 f32 into bf16 hi (truncated) + bf16 lo (rounded residual): ~16-bit mantissa total.
__device__ __forceinline__ void split8(const float* ap, short8& hi, short8& lo) {
  float4 a0 = *(const float4*)ap, a1 = *(const float4*)(ap + 4);
  float e[8] = {a0.x, a0.y, a0.z, a0.w, a1.x, a1.y, a1.z, a1.w};
  u16 h[8], l[8];
  #pragma unroll
  for (int j = 0; j < 8; ++j) {
    u32 b = __float_as_uint(e[j]);
    h[j] = (u16)(b >> 16);
    l[j] = f2bf(e[j] - u2f(b & 0xffff0000u));
  }
  hi = *(short8*)h; lo = *(short8*)l;
}
// Stage a 128x64 f32 chunk into LDS bf16 [128][72], 256-thread version.
__device__ __forceinline__ void stage_w(const float* g, int stride, int c, u16* Wl, int t) {
  int row = t >> 1, half = t & 1;
  const float4* gp = (const float4*)(g + (size_t)row * stride + c * 64 + half * 32);
  ushort8* d = (ushort8*)(Wl + row * 72 + half * 32);
  #pragma unroll
  for (int i = 0; i < 4; ++i) {
    float4 a = gp[2 * i], b = gp[2 * i + 1];
    ushort8 o;
    o[0] = f2bf(a.x); o[1] = f2bf(a.y); o[2] = f2bf(a.z); o[3] = f2bf(a.w);
    o[4] = f2bf(b.x); o[5] = f2bf(b.y); o[6] = f2bf(b.z); o[7] = f2bf(b.w);
    d[i] = o;
  }
}
// Same, 512-thread version (each thread 16 cols of one row).
__device__ __forceinline__ void stage_w512(const float* g, int stride, int c, u16* Wl, int t) {
  int row = t >> 2, q = t & 3;
  const float4* gp = (const float4*)(g + (size_t)row * stride + c * 64 + q * 16);
  ushort8* d = (ushort8*)(Wl + row * 72 + q * 16);
  #pragma unroll
  for (int i = 0; i < 2; ++i) {
    float4 a = gp[2 * i], b = gp[2 * i + 1];
    ushort8 o;
    o[0] = f2bf(a.x); o[1] = f2bf(a.y); o[2] = f2bf(a.z); o[3] = f2bf(a.w);
    o[4] = f2bf(b.x); o[5] = f2bf(b.y); o[6] = f2bf(b.z); o[7] = f2bf(b.w);
    d[i] = o;
  }
}

// K_prep: blocks 0..63: B for td-GEMM, pre-split bf16 (Bh/Bl[(k*64+z1)*64+z2]);
//         blocks 64..319: WW2[ho][kk*128+hi] = (1/16) sum_j F1w1[ho][kk*128+j]*F2w2[j][hi]
__global__ __launch_bounds__(256) void k_prep(const float* __restrict__ Ws,
                                              const float* __restrict__ Wd,
                                              const float* __restrict__ F1w1,
                                              const float* __restrict__ F2w2,
                                              u16* __restrict__ Bh, u16* __restrict__ Bl,
                                              float* __restrict__ WW2) {
  if (blockIdx.x < 64) {
    int t = blockIdx.x * 256 + threadIdx.x;     // 16384 = k(4) x z1(64) x z2(64)
    int k = t >> 12, z1 = (t >> 6) & 63, z2 = t & 63;
    const float* wsp = Ws + k * 8192 + z1;
    const float* wdp = Wd + k * 8192 + z2;
    float acc = 0.f;
    #pragma unroll 8
    for (int h = 0; h < 128; ++h) acc += wsp[h * 64] * wdp[h * 64];
    u32 b = __float_as_uint(acc);
    Bh[(k * 64 + z1) * 64 + z2] = (u16)(b >> 16);
    Bl[(k * 64 + z1) * 64 + z2] = f2bf(acc - u2f(b & 0xffff0000u));
  } else {
    int id = (blockIdx.x - 64) * 256 + threadIdx.x;  // 65536 = 128 ho x 4 kk x 128 hi
    int ho = id >> 9, kk = (id >> 7) & 3, hi = id & 127;
    const float* wa = F1w1 + ho * 512 + kk * 128;
    const float* wb = F2w2 + hi;
    float acc = 0.f;
    #pragma unroll 8
    for (int j = 0; j < 128; ++j) acc += wa[j] * wb[j * 128];
    WW2[ho * 512 + kk * 128 + hi] = acc * 0.0625f;
  }
}

// K_tduv, small-tile version (18.4 KB LDS, grid 1536):
//  blocks 0..1023:  td tile = 128 rows x 64 cols. rowtile=bid>>2, colquarter=bid&3.
//  blocks 1024..1535: u or v tile = 128 rows x 128 cols. sel=(bid-1024)>>8.
__global__ __launch_bounds__(256) void k_tduv(const float* __restrict__ zIG,
                                              const u16* __restrict__ Bh_g,
                                              const u16* __restrict__ Bl_g,
                                              const float* __restrict__ xt,
                                              const float* __restrict__ W1,
                                              float* __restrict__ td,
                                              u16* __restrict__ u, u16* __restrict__ v) {
  __shared__ __align__(16) u16 SM[128 * 72];   // td: Bh=SM[0:64*72), Bl=SM[64*72:); uv: full Wl
  int t = threadIdx.x, lane = t & 63, w = t >> 6;
  int l15 = lane & 15, kc = lane >> 4;
  if (blockIdx.x < 1024) {
    u16* Bh = SM;
    u16* Bl = SM + 64 * 72;
    int cq = blockIdx.x & 3;
    size_t rowbase = (size_t)(blockIdx.x >> 2) * 128 + w * 32;
    {  // stage B quarter: 64 cols x 64 z2, hi+lo
      int row = t >> 2, q = t & 3;
      const ushort8* gh = (const ushort8*)(Bh_g + (cq * 64 + row) * 64 + q * 16);
      const ushort8* gl = (const ushort8*)(Bl_g + (cq * 64 + row) * 64 + q * 16);
      ushort8* dh = (ushort8*)(Bh + row * 72 + q * 16);
      ushort8* dl = (ushort8*)(Bl + row * 72 + q * 16);
      dh[0] = gh[0]; dh[1] = gh[1];
      dl[0] = gl[0]; dl[1] = gl[1];
    }
    __syncthreads();
    f32x4 acc[2][4];
    #pragma unroll
    for (int mt = 0; mt < 2; ++mt)
      #pragma unroll
      for (int nt = 0; nt < 4; ++nt) acc[mt][nt] = (f32x4){0.f, 0.f, 0.f, 0.f};
    #pragma unroll
    for (int ks = 0; ks < 2; ++ks) {
      short8 ah[2], al[2];
      #pragma unroll
      for (int mt = 0; mt < 2; ++mt)
        split8(zIG + (rowbase + mt * 16 + l15) * 64 + ks * 32 + kc * 8, ah[mt], al[mt]);
      #pragma unroll
      for (int nt = 0; nt < 4; ++nt) {
        int bo = (nt * 16 + l15) * 72 + ks * 32 + kc * 8;
        short8 bh = *(const short8*)&Bh[bo];
        short8 bl = *(const short8*)&Bl[bo];
        #pragma unroll
        for (int mt = 0; mt < 2; ++mt) {
          acc[mt][nt] = __builtin_amdgcn_mfma_f32_16x16x32_bf16(ah[mt], bh, acc[mt][nt], 0, 0, 0);
          acc[mt][nt] = __builtin_amdgcn_mfma_f32_16x16x32_bf16(al[mt], bh, acc[mt][nt], 0, 0, 0);
          acc[mt][nt] = __builtin_amdgcn_mfma_f32_16x16x32_bf16(ah[mt], bl, acc[mt][nt], 0, 0, 0);
        }
      }
    }
    #pragma unroll
    for (int mt = 0; mt < 2; ++mt)
      #pragma unroll
      for (int nt = 0; nt < 4; ++nt)
        #pragma unroll
        for (int j = 0; j < 4; ++j)
          td[(rowbase + mt * 16 + kc * 4 + j) * 256 + cq * 64 + nt * 16 + l15] =
              acc[mt][nt][j];
  } else {
    u16* Wl = SM;
    int bid2 = blockIdx.x - 1024;
    int sel = bid2 >> 8;                       // 0 = u, 1 = v
    size_t rowbase = (size_t)(bid2 & 255) * 128 + w * 32;
    const float* Wbase = W1 + sel * 128;
    f32x4 acc[2][8];
    #pragma unroll
    for (int mt = 0; mt < 2; ++mt)
      #pragma unroll
      for (int nt = 0; nt < 8; ++nt) acc[mt][nt] = (f32x4){0.f, 0.f, 0.f, 0.f};
    for (int c = 0; c < 2; ++c) {
      __syncthreads();
      stage_w(Wbase, 256, c, Wl, t);
      __syncthreads();
      #pragma unroll
      for (int ks = 0; ks < 2; ++ks) {
        short8 af[2];
        #pragma unroll
        for (int mt = 0; mt < 2; ++mt) {
          const float* ap = xt + (rowbase + mt * 16 + l15) * 128 + c * 64 + ks * 32 + kc * 8;
          float4 a0 = *(const float4*)ap, a1 = *(const float4*)(ap + 4);
          u16 tmp[8] = {f2bf(a0.x), f2bf(a0.y), f2bf(a0.z), f2bf(a0.w),
                        f2bf(a1.x), f2bf(a1.y), f2bf(a1.z), f2bf(a1.w)};
          af[mt] = *(short8*)tmp;
        }
        #pragma unroll
        for (int nt = 0; nt < 8; ++nt) {
          short8 bw = *(const short8*)&Wl[(nt * 16 + l15) * 72 + ks * 32 + kc * 8];
          #pragma unroll
          for (int mt = 0; mt < 2; ++mt)
            acc[mt][nt] = __builtin_amdgcn_mfma_f32_16x16x32_bf16(af[mt], bw, acc[mt][nt], 0, 0, 0);
        }
      }
    }
    u16* dstp = sel ? v : u;
    #pragma unroll
    for (int mt = 0; mt < 2; ++mt)
      #pragma unroll
      for (int nt = 0; nt < 8; ++nt)
        #pragma unroll
        for (int j = 0; j < 4; ++j)
          dstp[(rowbase + mt * 16 + kc * 4 + j) * 128 + nt * 16 + l15] =
              f2bf(acc[mt][nt][j]);
  }
}

// K_score: fused per-node edge-attention + softmax + mailbox.
//  - u gathers issued right after barrier 1 (T14: latency hidden under phases B+C)
//    into 16 statically-indexed registers (spill-proof, unlike R8's [2][16]).
//  - per-thread redundant softmax: 3 barriers total, ~6.8 KB LDS.
__global__ __launch_bounds__(256) void k_score(
    const float* __restrict__ zIG, const int* __restrict__ src,
    const float* __restrict__ td, const u16* __restrict__ uW, const u16* __restrict__ vW,
    float* __restrict__ out, u16* __restrict__ m_ws) {
  __shared__ int srcIdx[16];
  __shared__ float tds[16 * 68];   // [sk][z] pad 68
  __shared__ float s17[16 * 17];   // scores [d][sk]
  __shared__ float a20[16 * 20];   // alpha  [d][s*4+k], float4-readable per (d,s)

  int t = threadIdx.x, n = blockIdx.x;
  if (t < 16) srcIdx[t] = src[n * 16 + t];
  {
    int r = t >> 4, cc = t & 15;
    *(float4*)&tds[r * 68 + cc * 4] = ((const float4*)(td + (size_t)n * 1024))[r * 16 + cc];
  }
  __syncthreads();
  // --- issue phase-D gathers NOW (consumed after softmax; latency hidden) ---
  int hp = t & 63, sD = t >> 6;
  const u32* up = (const u32*)uW;
  u32 upre[16];
  #pragma unroll
  for (int dd = 0; dd < 16; ++dd)
    upre[dd] = up[(size_t)srcIdx[dd] * 256 + sD * 64 + hp];
  u32 vbits = *(const u32*)(vW + (size_t)n * 512 + sD * 128 + hp * 2);
  {  // phase B: scores + leaky_relu; quad lane k loads interleaved quarter of the z row.
    int d = t >> 4, s = (t >> 2) & 3, k = t & 3;
    int sn = srcIdx[d];
    const float4* zp = (const float4*)(zIG + (size_t)sn * 256 + s * 64);
    int base = s * 4;
    float p0 = 0.f, p1 = 0.f, p2 = 0.f, p3 = 0.f;
    #pragma unroll
    for (int i = 0; i < 4; ++i) {
      float4 zv = zp[i * 4 + k];
      int o = i * 16 + k * 4;
      p0 += dot4(zv, *(const float4*)&tds[(base + 0) * 68 + o]);
      p1 += dot4(zv, *(const float4*)&tds[(base + 1) * 68 + o]);
      p2 += dot4(zv, *(const float4*)&tds[(base + 2) * 68 + o]);
      p3 += dot4(zv, *(const float4*)&tds[(base + 3) * 68 + o]);
    }
    p0 += __shfl_xor(p0, 1); p1 += __shfl_xor(p1, 1);
    p2 += __shfl_xor(p2, 1); p3 += __shfl_xor(p3, 1);
    p0 += __shfl_xor(p0, 2); p1 += __shfl_xor(p1, 2);
    p2 += __shfl_xor(p2, 2); p3 += __shfl_xor(p3, 2);
    float acc = (k == 0) ? p0 : (k == 1) ? p1 : (k == 2) ? p2 : p3;
    s17[d * 17 + base + k] = acc > 0.f ? acc : 0.01f * acc;
  }
  __syncthreads();
  {  // phase C: per-thread redundant softmax over d, alpha -> out + LDS
    int d = t >> 4, sk = t & 15;
    float mx = -3.4e38f;
    #pragma unroll
    for (int dd = 0; dd < 16; ++dd) mx = fmaxf(mx, s17[dd * 17 + sk]);
    float sum = 0.f, eown = 0.f;
    #pragma unroll
    for (int dd = 0; dd < 16; ++dd) {
      float e = __expf(s17[dd * 17 + sk] - mx);
      sum += e;
      if (dd == d) eown = e;
    }
    float a = eown / sum;
    a20[d * 20 + sk] = a;
    out[4194304u + (unsigned)n * 256 + t] = a;  // alpha [N][16][4][4]
  }
  __syncthreads();
  {  // phase D: mailbox from preloaded u regs
    float v_lo = u2f(vbits << 16), v_hi = u2f(vbits & 0xffff0000u);
    float m0l = 0.f, m0h = 0.f, m1l = 0.f, m1h = 0.f;
    float m2l = 0.f, m2h = 0.f, m3l = 0.f, m3h = 0.f;
    #pragma unroll
    for (int dd = 0; dd < 16; ++dd) {
      u32 ub = upre[dd];
      float r_lo = fmaxf(u2f(ub << 16) + v_lo, 0.f);
      float r_hi = fmaxf(u2f(ub & 0xffff0000u) + v_hi, 0.f);
      float4 a = *(const float4*)&a20[dd * 20 + sD * 4];
      m0l += a.x * r_lo; m0h += a.x * r_hi;
      m1l += a.y * r_lo; m1h += a.y * r_hi;
      m2l += a.z * r_lo; m2h += a.z * r_hi;
      m3l += a.w * r_lo; m3h += a.w * r_hi;
    }
    u32* mp = (u32*)(m_ws + (size_t)n * 2048);
    mp[(sD * 4 + 0) * 64 + hp] = pack2bf(m0l, m0h);
    mp[(sD * 4 + 1) * 64 + hp] = pack2bf(m1l, m1h);
    mp[(sD * 4 + 2) * 64 + hp] = pack2bf(m2l, m2h);
    mp[(sD * 4 + 3) * 64 + hp] = pack2bf(m3l, m3h);
  }
}

// K4: fused F+G, 512 threads / 8 waves (16 rows per wave).
//   hid = relu(m_flat[row][512] @ WW2[128][512]^T); out = hid @ F1w2[128][128]^T
__global__ __launch_bounds__(512) void k_fg(const u16* __restrict__ A,
                                            const float* __restrict__ WF,
                                            const float* __restrict__ WG,
                                            float* __restrict__ out) {
  __shared__ u16 Wl[128 * 72];
  __shared__ u16 hidl[128 * 136];
  int t = threadIdx.x, lane = t & 63, w = t >> 6;
  size_t rowbase = (size_t)blockIdx.x * 128 + w * 16;
  int l15 = lane & 15, kc = lane >> 4;
  f32x4 acc[8];
  #pragma unroll
  for (int nt = 0; nt < 8; ++nt) acc[nt] = (f32x4){0.f, 0.f, 0.f, 0.f};
  for (int c = 0; c < 8; ++c) {
    __syncthreads();
    stage_w512(WF, 512, c, Wl, t);
    __syncthreads();
    #pragma unroll
    for (int ks = 0; ks < 2; ++ks) {
      short8 af = *(const short8*)(A + (rowbase + l15) * 512 + c * 64 + ks * 32 + kc * 8);
      #pragma unroll
      for (int nt = 0; nt < 8; ++nt) {
        short8 bf = *(const short8*)&Wl[(nt * 16 + l15) * 72 + ks * 32 + kc * 8];
        acc[nt] = __builtin_amdgcn_mfma_f32_16x16x32_bf16(af, bf, acc[nt], 0, 0, 0);
      }
    }
  }
  #pragma unroll
  for (int nt = 0; nt < 8; ++nt)
    #pragma unroll
    for (int j = 0; j < 4; ++j)
      hidl[(w * 16 + kc * 4 + j) * 136 + nt * 16 + l15] = f2bf(fmaxf(acc[nt][j], 0.f));
  f32x4 acc2[8];
  #pragma unroll
  for (int nt = 0; nt < 8; ++nt) acc2[nt] = (f32x4){0.f, 0.f, 0.f, 0.f};
  for (int c = 0; c < 2; ++c) {
    __syncthreads();
    stage_w512(WG, 128, c, Wl, t);
    __syncthreads();
    #pragma unroll
    for (int ks = 0; ks < 2; ++ks) {
      short8 af = *(const short8*)&hidl[(w * 16 + l15) * 136 + c * 64 + ks * 32 + kc * 8];
      #pragma unroll
      for (int nt = 0; nt < 8; ++nt) {
        short8 bf = *(const short8*)&Wl[(nt * 16 + l15) * 72 + ks * 32 + kc * 8];
        acc2[nt] = __builtin_amdgcn_mfma_f32_16x16x32_bf16(af, bf, acc2[nt], 0, 0, 0);
      }
    }
  }
  #pragma unroll
  for (int nt = 0; nt < 8; ++nt)
    #pragma unroll
    for (int j = 0; j < 4; ++j)
      out[(rowbase + kc * 4 + j) * 128 + nt * 16 + l15] = acc2[nt][j];
}

extern "C" void kernel_launch(void* const* d_in, const int* in_sizes, int n_in,
                              void* d_out, int out_size, void* d_ws, size_t ws_size,
                              hipStream_t stream) {
  const float* zIG  = (const float*)d_in[0];
  const float* xt   = (const float*)d_in[1];
  const float* Ws   = (const float*)d_in[2];
  const float* Wd   = (const float*)d_in[3];
  const float* F2w1 = (const float*)d_in[4];
  const float* F2w2 = (const float*)d_in[5];
  const float* F1w1 = (const float*)d_in[6];
  const float* F1w2 = (const float*)d_in[7];
  const int* src    = (const int*)d_in[8];
  float* out = (float*)d_out;

  char* ws = (char*)d_ws;
  u16* Bh    = (u16*)ws;                             // 32 KiB (td-GEMM B hi)
  u16* Bl    = Bh + 16384;                           // 32 KiB (td-GEMM B lo)
  float* td  = (float*)(ws + 65536);                 // 32 MiB
  u16* u     = (u16*)(ws + 65536 + 33554432);        // 8 MiB
  u16* v     = u + 4194304;                          // 8 MiB
  float* WW2 = (float*)(ws + 50397184);              // 256 KiB (composite F1w1@F2w2/16)
  u16* m     = (u16*)(ws + 50659328);                // 32 MiB

  k_prep <<<320,  256, 0, stream>>>(Ws, Wd, F1w1, F2w2, Bh, Bl, WW2);
  k_tduv <<<1536, 256, 0, stream>>>(zIG, Bh, Bl, xt, F2w1, td, u, v);
  k_score<<<8192, 256, 0, stream>>>(zIG, src, td, u, v, out, m);
  k_fg   <<<256,  512, 0, stream>>>(m, WW2, F1w2, out);
}